// Round 12
// baseline (147.832 us; speedup 1.0000x reference)
//
#include <hip/hip_runtime.h>

// SparseWindowedAttention: B=1, S=4096, E=768, H=12, hd=64, window=128
// R12 = R11 byte-identical + SECOND attn_win launch (pure measurement:
// total_R12 - total_R11 = attn_win duration; attn_win is idempotent).
//
//   c0: fused fp32->bf16 convert (x, Wqkv, Wo)
//   k1: qkv GEMM 128x96 (768 blocks = 3/CU), dbuf DMA; epilogue: V^T direct
//       8B stores, Q/K via LDS-round-trip -> 16B/lane coalesced stores
//   k2: windowed attention (x2 this round, measurement)
//   k3: out = attn @ Wo^T + bo, 64x64 dbuf GEMM; LDS-round-trip fp32 epilogue

typedef __attribute__((ext_vector_type(8))) short short8;
typedef __attribute__((ext_vector_type(4))) short short4v;
typedef __attribute__((ext_vector_type(4))) float f32x4;

#define S_LEN 4096
#define EMB   768
#define NH    12
#define HD    64
#define QT    64
#define WMAX  128
#define NKT   20
#define QSCALE 0.18033688f   // 1/sqrt(64) * log2(e); softmax base-2

#if defined(__HIP_DEVICE_COMPILE__)
#define MFMA16(a, b, c) __builtin_amdgcn_mfma_f32_16x16x16bf16_1k(a, b, c, 0, 0, 0)
#else
#define MFMA16(a, b, c) (c)
#endif

__device__ __forceinline__ short f2bf(float f) {
    union { unsigned int i; float f; } c;
    c.f = f;
    unsigned int i = c.i;
    unsigned int r = (i + 0x7FFFu + ((i >> 16) & 1u)) >> 16;
    return (short)(unsigned short)r;
}

// fused fp32->bf16: segments [x | Wqkv | Wo]
#define NX4  (S_LEN * EMB / 4)
#define NW4  (3 * EMB * EMB / 4)
#define NO4  (EMB * EMB / 4)
__global__ __launch_bounds__(256) void convert_all(
    const float* __restrict__ x, const float* __restrict__ wqkv,
    const float* __restrict__ wo, short* __restrict__ xb,
    short* __restrict__ wqkvb, short* __restrict__ wob)
{
    int i = blockIdx.x * 256 + threadIdx.x;
    const float* src; short* dst; int off;
    if (i < NX4)            { src = x;    dst = xb;    off = i; }
    else if (i < NX4 + NW4) { src = wqkv; dst = wqkvb; off = i - NX4; }
    else                    { src = wo;   dst = wob;   off = i - NX4 - NW4; }
    float4 v = ((const float4*)src)[off];
    short4v o = { f2bf(v.x), f2bf(v.y), f2bf(v.z), f2bf(v.w) };
    *(short4v*)(dst + (size_t)off * 4) = o;
}

// ---------------------------------------------------------------------------
// QKV GEMM: C = A·B^T + bias, 128(M)x96(N), BK=32, dbuf DMA, grid 24x32=768.
// Epilogue: V -> direct V^T 8B stores; Q/K -> LDS round-trip, short8 stores.
// ---------------------------------------------------------------------------
__global__ __launch_bounds__(256) void gemm_qkv(
    const short* __restrict__ A, const short* __restrict__ B,
    const float* __restrict__ bias, short* __restrict__ Cv,
    int M, int N, int K)
{
    __shared__ __align__(16) short smem[2 * 4096 + 2 * 3072];
    short* As0 = smem;
    short* Bs0 = smem + 2 * 4096;

    const int t = threadIdx.x;
    const int w = t >> 6, l = t & 63;
    const int quad = l >> 4, lane16 = l & 15;
    const int m0 = blockIdx.y * 128, n0 = blockIdx.x * 96;
    const int wm = (w >> 1) * 64, wn = (w & 1) * 48;

    f32x4 acc[4][3];
#pragma unroll
    for (int i = 0; i < 4; ++i)
#pragma unroll
        for (int j = 0; j < 3; ++j) acc[i][j] = (f32x4){0.f, 0.f, 0.f, 0.f};

    const int NKI = K >> 5;   // 24

    auto stage = [&](int ki, int b) {
        short* Asb = As0 + b * 4096;
        short* Bsb = Bs0 + b * 3072;
#pragma unroll
        for (int i = 0; i < 4; ++i) {
            int c = i * 256 + t;
            if (c < 512) {
                int r = c >> 2, kc = c & 3;
#if defined(__HIP_DEVICE_COMPILE__) && __has_builtin(__builtin_amdgcn_global_load_lds)
                __builtin_amdgcn_global_load_lds(
                    (const __attribute__((address_space(1))) void*)(A + (size_t)(m0 + r) * K + ki * 32 + kc * 8),
                    (__attribute__((address_space(3))) void*)(Asb + c * 8), 16, 0, 0);
#else
                *(short8*)(Asb + c * 8) = *(const short8*)(A + (size_t)(m0 + r) * K + ki * 32 + kc * 8);
#endif
            } else if (c < 896) {
                int cb = c - 512;
                int r = cb >> 2, kc = cb & 3;
#if defined(__HIP_DEVICE_COMPILE__) && __has_builtin(__builtin_amdgcn_global_load_lds)
                __builtin_amdgcn_global_load_lds(
                    (const __attribute__((address_space(1))) void*)(B + (size_t)(n0 + r) * K + ki * 32 + kc * 8),
                    (__attribute__((address_space(3))) void*)(Bsb + cb * 8), 16, 0, 0);
#else
                *(short8*)(Bsb + cb * 8) = *(const short8*)(B + (size_t)(n0 + r) * K + ki * 32 + kc * 8);
#endif
            }
        }
    };

    stage(0, 0);
    for (int kb = 0; kb < NKI; ++kb) {
        const int cur = kb & 1;
        __syncthreads();
        if (kb + 1 < NKI) stage(kb + 1, cur ^ 1);

        const short* Asb = As0 + cur * 4096;
        const short* Bsb = Bs0 + cur * 3072;
        short8 af[4], bfr[3];
#pragma unroll
        for (int mt = 0; mt < 4; ++mt)
            af[mt] = *(const short8*)(Asb + (wm + mt * 16 + lane16) * 32 + quad * 8);
#pragma unroll
        for (int nt = 0; nt < 3; ++nt)
            bfr[nt] = *(const short8*)(Bsb + (wn + nt * 16 + lane16) * 32 + quad * 8);
#pragma unroll
        for (int mt = 0; mt < 4; ++mt)
#pragma unroll
            for (int nt = 0; nt < 3; ++nt)
                acc[mt][nt] = __builtin_amdgcn_mfma_f32_16x16x32_bf16(
                    af[mt], bfr[nt], acc[mt][nt], 0, 0, 0);
    }

    __syncthreads();
    short(*Ct)[100] = (short(*)[100])smem;

#pragma unroll
    for (int nt = 0; nt < 3; ++nt) {
        int col = n0 + wn + nt * 16 + lane16;
        float bv = bias[col];
        int h = col / 192;
        int rem = col - h * 192;
        int ty = rem >> 6, d = rem & 63;
        if (ty == 2) {
            short* vt = Cv + ((size_t)2 * NH * S_LEN) * HD + ((size_t)h * HD + d) * S_LEN;
#pragma unroll
            for (int mt = 0; mt < 4; ++mt) {
                int row0 = m0 + wm + mt * 16 + quad * 4;
                short4v o = { f2bf(acc[mt][nt][0] + bv), f2bf(acc[mt][nt][1] + bv),
                              f2bf(acc[mt][nt][2] + bv), f2bf(acc[mt][nt][3] + bv) };
                *(short4v*)(vt + row0) = o;
            }
        } else {
            float s = (ty == 0) ? QSCALE : 1.f;
            int cl = wn + nt * 16 + lane16;
#pragma unroll
            for (int mt = 0; mt < 4; ++mt) {
#pragma unroll
                for (int r = 0; r < 4; ++r)
                    Ct[wm + mt * 16 + quad * 4 + r][cl] = f2bf((acc[mt][nt][r] + bv) * s);
            }
        }
    }
    __syncthreads();

#pragma unroll
    for (int pass = 0; pass < 6; ++pass) {
        int c = pass * 256 + t;
        int row = c / 12, cg = c - row * 12;
        int col0 = n0 + cg * 8;
        int h = col0 / 192;
        int rem = col0 - h * 192;
        int ty = rem >> 6;
        if (ty == 2) continue;
        int d0 = rem - ty * 64;
        short* dst = Cv + (((size_t)ty * NH + h) * S_LEN + (m0 + row)) * HD + d0;
        *(short8*)dst = *(const short8*)(&Ct[row][cg * 8]);
    }
}

// ---------------------------------------------------------------------------
// Windowed attention (unchanged from R11).
// ---------------------------------------------------------------------------
__global__ __launch_bounds__(256, 3) void attn_win(
    const short* __restrict__ qsplit, const int* __restrict__ wptr,
    short* __restrict__ attn_out)
{
    __shared__ __align__(16) short KS[320 * 64];   // 40960 B

    const int t = threadIdx.x;
    const int w = t >> 6, l = t & 63;
    const int quad = l >> 4, lane16 = l & 15;

    const int id = blockIdx.x;
    const int xcd = id & 7, j = id >> 3;
    const int h = j >> 3;
    const int q0 = ((xcd << 3) + (j & 7)) * QT;
    const int W = *wptr;
    const int kbase = q0 - WMAX;

    const short* Qh  = qsplit + (size_t)h * S_LEN * HD;
    const short* Kh  = qsplit + (size_t)(NH + h) * S_LEN * HD;
    const short* VtG = qsplit + (size_t)2 * NH * S_LEN * HD + (size_t)h * HD * S_LEN;

#pragma unroll
    for (int i = 0; i < 10; ++i) {
        int c = i * 256 + t;
        int r = c >> 3, gs = c & 7;
        int g = gs ^ (r & 7);
        int idx = min(max(kbase + r, 0), S_LEN - 1);
#if defined(__HIP_DEVICE_COMPILE__) && __has_builtin(__builtin_amdgcn_global_load_lds)
        __builtin_amdgcn_global_load_lds(
            (const __attribute__((address_space(1))) void*)(Kh + (size_t)idx * HD + g * 8),
            (__attribute__((address_space(3))) void*)(KS + c * 8), 16, 0, 0);
#else
        *(short8*)(KS + c * 8) = *(const short8*)(Kh + (size_t)idx * HD + g * 8);
#endif
    }
    const int qi = q0 + w * 16 + lane16;
    const short* qp = Qh + (size_t)qi * HD;
    short8 bq0 = *(const short8*)(qp + quad * 8);
    short8 bq1 = *(const short8*)(qp + 32 + quad * 8);

    __syncthreads();   // K resident

    f32x4 sc[NKT];
    const int d7 = lane16 & 7;
    const int s0 = (quad ^ d7) * 8;
    const int s1 = ((quad + 4) ^ d7) * 8;
#pragma unroll
    for (int kt = 0; kt < NKT; ++kt) {
        const short* kp = KS + (kt * 16 + lane16) * 64;
        short8 a0 = *(const short8*)(kp + s0);
        short8 a1 = *(const short8*)(kp + s1);
        f32x4 a = (f32x4){0.f, 0.f, 0.f, 0.f};
        a = __builtin_amdgcn_mfma_f32_16x16x32_bf16(a0, bq0, a, 0, 0, 0);
        a = __builtin_amdgcn_mfma_f32_16x16x32_bf16(a1, bq1, a, 0, 0, 0);
        sc[kt] = a;
    }

    __syncthreads();   // WAR: K reads done; KS free for V^T

#pragma unroll
    for (int i = 0; i < 10; ++i) {
        int c = i * 256 + t;
        int d = c / 40;
        int slot = c - d * 40;
        int sg = slot >> 3, s = slot & 7;
        int g = s ^ (d & 7);
        int key0 = kbase + sg * 64 + g * 8;
        key0 = min(max(key0, 0), S_LEN - 8);
#if defined(__HIP_DEVICE_COMPILE__) && __has_builtin(__builtin_amdgcn_global_load_lds)
        __builtin_amdgcn_global_load_lds(
            (const __attribute__((address_space(1))) void*)(VtG + (size_t)d * S_LEN + key0),
            (__attribute__((address_space(3))) void*)(KS + c * 8), 16, 0, 0);
#else
        *(short8*)(KS + c * 8) = *(const short8*)(VtG + (size_t)d * S_LEN + key0);
#endif
    }

    float m = -1e30f;
#pragma unroll
    for (int kt = 0; kt < NKT; ++kt) {
#pragma unroll
        for (int r = 0; r < 4; ++r) {
            int key = kbase + kt * 16 + quad * 4 + r;
            int dd = qi - key;
            int ad = dd < 0 ? -dd : dd;
            bool valid = ((unsigned)key < S_LEN) && (ad <= W);
            float s = valid ? sc[kt][r] : -1e30f;
            sc[kt][r] = s;
            m = fmaxf(m, s);
        }
    }
    m = fmaxf(m, __shfl_xor(m, 16, 64));
    m = fmaxf(m, __shfl_xor(m, 32, 64));

    float lsum = 0.f;
#pragma unroll
    for (int kt = 0; kt < NKT; ++kt) {
#pragma unroll
        for (int r = 0; r < 4; ++r) {
            float p = exp2f(sc[kt][r] - m);
            sc[kt][r] = p;
            lsum += p;
        }
    }
    lsum += __shfl_xor(lsum, 16, 64);
    lsum += __shfl_xor(lsum, 32, 64);
    const float rl = 1.f / fmaxf(lsum, 1e-30f);

    __syncthreads();   // V^T resident

    f32x4 oacc[4];
#pragma unroll
    for (int nt = 0; nt < 4; ++nt) oacc[nt] = (f32x4){0.f, 0.f, 0.f, 0.f};

#pragma unroll
    for (int kt = 0; kt < NKT; ++kt) {
        short4v pb = { f2bf(sc[kt][0]), f2bf(sc[kt][1]),
                       f2bf(sc[kt][2]), f2bf(sc[kt][3]) };
        int G = kt * 2 + (quad >> 1);
        int off = (G >> 3) * 64 + ((G & 7) ^ d7) * 8 + (quad & 1) * 4;
#pragma unroll
        for (int nt = 0; nt < 4; ++nt) {
            short4v va = *(const short4v*)(KS + (nt * 16 + lane16) * 320 + off);
            oacc[nt] = MFMA16(va, pb, oacc[nt]);
        }
    }

#pragma unroll
    for (int nt = 0; nt < 4; ++nt) {
        short4v ob = { f2bf(oacc[nt][0] * rl), f2bf(oacc[nt][1] * rl),
                       f2bf(oacc[nt][2] * rl), f2bf(oacc[nt][3] * rl) };
        *(short4v*)(attn_out + (size_t)qi * EMB + h * HD + nt * 16 + quad * 4) = ob;
    }
}

// ---------------------------------------------------------------------------
// Output projection GEMM (unchanged from R11).
// ---------------------------------------------------------------------------
__global__ __launch_bounds__(256) void gemm_out64(
    const short* __restrict__ A, const short* __restrict__ B,
    const float* __restrict__ bias, float* __restrict__ C,
    int M, int N, int K)
{
    __shared__ __align__(16) short As[2][4352];
    __shared__ __align__(16) short Bs[2][4096];

    const int t = threadIdx.x;
    const int w = t >> 6, l = t & 63;
    const int quad = l >> 4, lane16 = l & 15;
    const int m0 = blockIdx.y * 64, n0 = blockIdx.x * 64;
    const int wm = (w >> 1) * 32, wn = (w & 1) * 32;

    f32x4 acc[2][2];
#pragma unroll
    for (int i = 0; i < 2; ++i)
#pragma unroll
        for (int j = 0; j < 2; ++j) acc[i][j] = (f32x4){0.f, 0.f, 0.f, 0.f};

    const int NKI = K >> 6;   // 12

    auto stage = [&](int ki, int b) {
#pragma unroll
        for (int i = 0; i < 2; ++i) {
            int c = i * 256 + t;
            int r = c >> 3, kc = c & 7;
            int g = kc ^ (r & 7);
#if defined(__HIP_DEVICE_COMPILE__) && __has_builtin(__builtin_amdgcn_global_load_lds)
            __builtin_amdgcn_global_load_lds(
                (const __attribute__((address_space(1))) void*)(A + (size_t)(m0 + r) * K + ki * 64 + g * 8),
                (__attribute__((address_space(3))) void*)(As[b] + c * 8), 16, 0, 0);
            __builtin_amdgcn_global_load_lds(
                (const __attribute__((address_space(1))) void*)(B + (size_t)(n0 + r) * K + ki * 64 + g * 8),
                (__attribute__((address_space(3))) void*)(Bs[b] + c * 8), 16, 0, 0);
#else
            *(short8*)(As[b] + c * 8) = *(const short8*)(A + (size_t)(m0 + r) * K + ki * 64 + g * 8);
            *(short8*)(Bs[b] + c * 8) = *(const short8*)(B + (size_t)(n0 + r) * K + ki * 64 + g * 8);
#endif
        }
    };

    stage(0, 0);
    for (int kb = 0; kb < NKI; ++kb) {
        const int cur = kb & 1;
        __syncthreads();
        if (kb + 1 < NKI) stage(kb + 1, cur ^ 1);

#pragma unroll
        for (int ks = 0; ks < 2; ++ks) {
            short8 af[2], bfr[2];
#pragma unroll
            for (int mt = 0; mt < 2; ++mt) {
                int row = wm + mt * 16 + lane16;
                int slot = (ks * 4 + quad) ^ (row & 7);
                af[mt] = *(const short8*)(As[cur] + row * 64 + slot * 8);
            }
#pragma unroll
            for (int nt = 0; nt < 2; ++nt) {
                int row = wn + nt * 16 + lane16;
                int slot = (ks * 4 + quad) ^ (row & 7);
                bfr[nt] = *(const short8*)(Bs[cur] + row * 64 + slot * 8);
            }
#pragma unroll
            for (int mt = 0; mt < 2; ++mt)
#pragma unroll
                for (int nt = 0; nt < 2; ++nt)
                    acc[mt][nt] = __builtin_amdgcn_mfma_f32_16x16x32_bf16(
                        af[mt], bfr[nt], acc[mt][nt], 0, 0, 0);
        }
    }

    __syncthreads();
    float(*Ct)[66] = (float(*)[66])As;

#pragma unroll
    for (int nt = 0; nt < 2; ++nt) {
        int cl = wn + nt * 16 + lane16;
        float bv = bias[n0 + cl];
#pragma unroll
        for (int mt = 0; mt < 2; ++mt) {
#pragma unroll
            for (int r = 0; r < 4; ++r)
                Ct[wm + mt * 16 + quad * 4 + r][cl] = acc[mt][nt][r] + bv;
        }
    }
    __syncthreads();

#pragma unroll
    for (int pass = 0; pass < 4; ++pass) {
        int c = pass * 256 + t;
        int row = c >> 4, cg = c & 15;
        float4 v = { Ct[row][cg * 4], Ct[row][cg * 4 + 1],
                     Ct[row][cg * 4 + 2], Ct[row][cg * 4 + 3] };
        *(float4*)(C + (size_t)(m0 + row) * N + n0 + cg * 4) = v;
    }
}

extern "C" void kernel_launch(void* const* d_in, const int* in_sizes, int n_in,
                              void* d_out, int out_size, void* d_ws, size_t ws_size,
                              hipStream_t stream) {
    const float* x    = (const float*)d_in[0];
    const float* Wqkv = (const float*)d_in[1];
    const float* bqkv = (const float*)d_in[2];
    const float* Wo   = (const float*)d_in[3];
    const float* bo   = (const float*)d_in[4];
    const int*   wptr = (const int*)d_in[5];

    float* out = (float*)d_out;

    short* xb     = (short*)d_ws;
    short* wqkvb  = xb     + (size_t)S_LEN * EMB;
    short* wob    = wqkvb  + (size_t)3 * EMB * EMB;
    short* qsplit = wob    + (size_t)EMB * EMB;
    short* attn   = qsplit + (size_t)3 * NH * S_LEN * HD;

    dim3 blk(256);
    convert_all<<<dim3((NX4 + NW4 + NO4) / 256), blk, 0, stream>>>(
        x, Wqkv, Wo, xb, wqkvb, wob);
    gemm_qkv<<<dim3(2304 / 96, S_LEN / 128), blk, 0, stream>>>(
        xb, wqkvb, bqkv, qsplit, S_LEN, 2304, EMB);
    // MEASUREMENT (R12): attn_win launched twice, idempotent. The total-time
    // delta vs R11 (134.2 us) measures attn_win's duration directly.
    attn_win<<<dim3(S_LEN / QT * NH), blk, 0, stream>>>(qsplit, wptr, attn);
    attn_win<<<dim3(S_LEN / QT * NH), blk, 0, stream>>>(qsplit, wptr, attn);
    gemm_out64<<<dim3(EMB / 64, S_LEN / 64), blk, 0, stream>>>(
        attn, wob, bo, out, S_LEN, EMB, EMB);
}

// Round 13
// 139.751 us; speedup vs baseline: 1.0578x; 1.0578x over previous
//
#include <hip/hip_runtime.h>

// SparseWindowedAttention: B=1, S=4096, E=768, H=12, hd=64, window=128
// Inputs fp32, output fp32. MFMA bf16 w/ fp32 accum. NO separate convert
// kernel: fp32->bf16 happens in-register during GEMM staging.
//
//   k1: qkv GEMM 128x96 (768 blocks = 3/CU), reg-staged fp32->bf16 dbuf;
//       epilogue: V^T direct 8B stores, Q/K via LDS-round-trip coalesced
//   k2: windowed attention (unchanged from R11, single launch)
//   k3: out = attn @ Wo^T + bo, 64x64 dbuf (A: bf16 DMA; B: Wo fp32 reg-staged)

typedef __attribute__((ext_vector_type(8))) short short8;
typedef __attribute__((ext_vector_type(4))) short short4v;
typedef __attribute__((ext_vector_type(4))) float f32x4;

#define S_LEN 4096
#define EMB   768
#define NH    12
#define HD    64
#define QT    64
#define WMAX  128
#define NKT   20
#define QSCALE 0.18033688f   // 1/sqrt(64) * log2(e); softmax base-2

#if defined(__HIP_DEVICE_COMPILE__)
#define MFMA16(a, b, c) __builtin_amdgcn_mfma_f32_16x16x16bf16_1k(a, b, c, 0, 0, 0)
#else
#define MFMA16(a, b, c) (c)
#endif

__device__ __forceinline__ short f2bf(float f) {
    union { unsigned int i; float f; } c;
    c.f = f;
    unsigned int i = c.i;
    unsigned int r = (i + 0x7FFFu + ((i >> 16) & 1u)) >> 16;
    return (short)(unsigned short)r;
}
__device__ __forceinline__ short8 cvt8(f32x4 a, f32x4 b) {
    short8 o;
#pragma unroll
    for (int j = 0; j < 4; ++j) { o[j] = f2bf(a[j]); o[4 + j] = f2bf(b[j]); }
    return o;
}

// ---------------------------------------------------------------------------
// QKV GEMM: C = A·B^T + bias, A=x fp32 [4096][768], B=Wqkv fp32 [2304][768].
// 128(M)x96(N), BK=32, dbuf; staging = reg loads (fp32) + in-reg cvt + ds_write.
// Loads issued right AFTER the barrier -> compute phase covers their latency;
// cvt VALU runs in the load shadow. Epilogue: V^T direct, Q/K LDS round-trip.
// ---------------------------------------------------------------------------
__global__ __launch_bounds__(256) void gemm_qkv(
    const float* __restrict__ A, const float* __restrict__ B,
    const float* __restrict__ bias, short* __restrict__ Cv,
    int M, int N, int K)
{
    __shared__ __align__(16) short smem[2 * 4096 + 2 * 3072];   // 28 KB
    short* As0 = smem;
    short* Bs0 = smem + 2 * 4096;

    const int t = threadIdx.x;
    const int w = t >> 6, l = t & 63;
    const int quad = l >> 4, lane16 = l & 15;
    const int m0 = blockIdx.y * 128, n0 = blockIdx.x * 96;
    const int wm = (w >> 1) * 64, wn = (w & 1) * 48;

    f32x4 acc[4][3];
#pragma unroll
    for (int i = 0; i < 4; ++i)
#pragma unroll
        for (int j = 0; j < 3; ++j) acc[i][j] = (f32x4){0.f, 0.f, 0.f, 0.f};

    const int NKI = K >> 5;   // 24

    // staging registers: A chunks c=t, t+256 (8 floats each); B chunks t, 256+t(t<128)
    f32x4 ra[2][2], rb[2][2];

    auto loadg = [&](int ki) {
#pragma unroll
        for (int i = 0; i < 2; ++i) {
            int c = i * 256 + t;
            int r = c >> 2, kc = c & 3;
            const float* p = A + (size_t)(m0 + r) * K + ki * 32 + kc * 8;
            ra[i][0] = *(const f32x4*)p;
            ra[i][1] = *(const f32x4*)(p + 4);
        }
        {
            int r = t >> 2, kc = t & 3;
            const float* p = B + (size_t)(n0 + r) * K + ki * 32 + kc * 8;
            rb[0][0] = *(const f32x4*)p;
            rb[0][1] = *(const f32x4*)(p + 4);
        }
        if (t < 128) {   // wave-uniform (waves 0,1)
            int cb = 256 + t;
            int r = cb >> 2, kc = cb & 3;
            const float* p = B + (size_t)(n0 + r) * K + ki * 32 + kc * 8;
            rb[1][0] = *(const f32x4*)p;
            rb[1][1] = *(const f32x4*)(p + 4);
        }
    };
    auto cvtwrite = [&](int b) {
        short* Asb = As0 + b * 4096;
        short* Bsb = Bs0 + b * 3072;
#pragma unroll
        for (int i = 0; i < 2; ++i) {
            int c = i * 256 + t;
            *(short8*)(Asb + c * 8) = cvt8(ra[i][0], ra[i][1]);
        }
        *(short8*)(Bsb + t * 8) = cvt8(rb[0][0], rb[0][1]);
        if (t < 128)
            *(short8*)(Bsb + (256 + t) * 8) = cvt8(rb[1][0], rb[1][1]);
    };

    loadg(0);
    cvtwrite(0);
    for (int kb = 0; kb < NKI; ++kb) {
        const int cur = kb & 1;
        __syncthreads();                       // buf[cur] visible; prev reads done
        if (kb + 1 < NKI) loadg(kb + 1);       // fp32 loads in flight over compute

        const short* Asb = As0 + cur * 4096;
        const short* Bsb = Bs0 + cur * 3072;
        short8 af[4], bfr[3];
#pragma unroll
        for (int mt = 0; mt < 4; ++mt)
            af[mt] = *(const short8*)(Asb + (wm + mt * 16 + lane16) * 32 + quad * 8);
#pragma unroll
        for (int nt = 0; nt < 3; ++nt)
            bfr[nt] = *(const short8*)(Bsb + (wn + nt * 16 + lane16) * 32 + quad * 8);
#pragma unroll
        for (int mt = 0; mt < 4; ++mt)
#pragma unroll
            for (int nt = 0; nt < 3; ++nt)
                acc[mt][nt] = __builtin_amdgcn_mfma_f32_16x16x32_bf16(
                    af[mt], bfr[nt], acc[mt][nt], 0, 0, 0);

        if (kb + 1 < NKI) cvtwrite(cur ^ 1);   // vmcnt wait lands here, post-compute
    }

    __syncthreads();   // all reads done; smem free for epilogue tile
    short(*Ct)[100] = (short(*)[100])smem;

#pragma unroll
    for (int nt = 0; nt < 3; ++nt) {
        int col = n0 + wn + nt * 16 + lane16;
        float bv = bias[col];
        int h = col / 192;
        int rem = col - h * 192;
        int ty = rem >> 6, d = rem & 63;
        if (ty == 2) {
            short* vt = Cv + ((size_t)2 * NH * S_LEN) * HD + ((size_t)h * HD + d) * S_LEN;
#pragma unroll
            for (int mt = 0; mt < 4; ++mt) {
                int row0 = m0 + wm + mt * 16 + quad * 4;
                short4v o = { f2bf(acc[mt][nt][0] + bv), f2bf(acc[mt][nt][1] + bv),
                              f2bf(acc[mt][nt][2] + bv), f2bf(acc[mt][nt][3] + bv) };
                *(short4v*)(vt + row0) = o;
            }
        } else {
            float s = (ty == 0) ? QSCALE : 1.f;
            int cl = wn + nt * 16 + lane16;
#pragma unroll
            for (int mt = 0; mt < 4; ++mt) {
#pragma unroll
                for (int r = 0; r < 4; ++r)
                    Ct[wm + mt * 16 + quad * 4 + r][cl] = f2bf((acc[mt][nt][r] + bv) * s);
            }
        }
    }
    __syncthreads();

#pragma unroll
    for (int pass = 0; pass < 6; ++pass) {
        int c = pass * 256 + t;
        int row = c / 12, cg = c - row * 12;
        int col0 = n0 + cg * 8;
        int h = col0 / 192;
        int rem = col0 - h * 192;
        int ty = rem >> 6;
        if (ty == 2) continue;
        int d0 = rem - ty * 64;
        short* dst = Cv + (((size_t)ty * NH + h) * S_LEN + (m0 + row)) * HD + d0;
        *(short8*)dst = *(const short8*)(&Ct[row][cg * 8]);
    }
}

// ---------------------------------------------------------------------------
// Windowed attention (unchanged from R11).
// ---------------------------------------------------------------------------
__global__ __launch_bounds__(256, 3) void attn_win(
    const short* __restrict__ qsplit, const int* __restrict__ wptr,
    short* __restrict__ attn_out)
{
    __shared__ __align__(16) short KS[320 * 64];   // 40960 B

    const int t = threadIdx.x;
    const int w = t >> 6, l = t & 63;
    const int quad = l >> 4, lane16 = l & 15;

    const int id = blockIdx.x;
    const int xcd = id & 7, j = id >> 3;
    const int h = j >> 3;
    const int q0 = ((xcd << 3) + (j & 7)) * QT;
    const int W = *wptr;
    const int kbase = q0 - WMAX;

    const short* Qh  = qsplit + (size_t)h * S_LEN * HD;
    const short* Kh  = qsplit + (size_t)(NH + h) * S_LEN * HD;
    const short* VtG = qsplit + (size_t)2 * NH * S_LEN * HD + (size_t)h * HD * S_LEN;

#pragma unroll
    for (int i = 0; i < 10; ++i) {
        int c = i * 256 + t;
        int r = c >> 3, gs = c & 7;
        int g = gs ^ (r & 7);
        int idx = min(max(kbase + r, 0), S_LEN - 1);
#if defined(__HIP_DEVICE_COMPILE__) && __has_builtin(__builtin_amdgcn_global_load_lds)
        __builtin_amdgcn_global_load_lds(
            (const __attribute__((address_space(1))) void*)(Kh + (size_t)idx * HD + g * 8),
            (__attribute__((address_space(3))) void*)(KS + c * 8), 16, 0, 0);
#else
        *(short8*)(KS + c * 8) = *(const short8*)(Kh + (size_t)idx * HD + g * 8);
#endif
    }
    const int qi = q0 + w * 16 + lane16;
    const short* qp = Qh + (size_t)qi * HD;
    short8 bq0 = *(const short8*)(qp + quad * 8);
    short8 bq1 = *(const short8*)(qp + 32 + quad * 8);

    __syncthreads();   // K resident

    f32x4 sc[NKT];
    const int d7 = lane16 & 7;
    const int s0 = (quad ^ d7) * 8;
    const int s1 = ((quad + 4) ^ d7) * 8;
#pragma unroll
    for (int kt = 0; kt < NKT; ++kt) {
        const short* kp = KS + (kt * 16 + lane16) * 64;
        short8 a0 = *(const short8*)(kp + s0);
        short8 a1 = *(const short8*)(kp + s1);
        f32x4 a = (f32x4){0.f, 0.f, 0.f, 0.f};
        a = __builtin_amdgcn_mfma_f32_16x16x32_bf16(a0, bq0, a, 0, 0, 0);
        a = __builtin_amdgcn_mfma_f32_16x16x32_bf16(a1, bq1, a, 0, 0, 0);
        sc[kt] = a;
    }

    __syncthreads();   // WAR: K reads done; KS free for V^T

#pragma unroll
    for (int i = 0; i < 10; ++i) {
        int c = i * 256 + t;
        int d = c / 40;
        int slot = c - d * 40;
        int sg = slot >> 3, s = slot & 7;
        int g = s ^ (d & 7);
        int key0 = kbase + sg * 64 + g * 8;
        key0 = min(max(key0, 0), S_LEN - 8);
#if defined(__HIP_DEVICE_COMPILE__) && __has_builtin(__builtin_amdgcn_global_load_lds)
        __builtin_amdgcn_global_load_lds(
            (const __attribute__((address_space(1))) void*)(VtG + (size_t)d * S_LEN + key0),
            (__attribute__((address_space(3))) void*)(KS + c * 8), 16, 0, 0);
#else
        *(short8*)(KS + c * 8) = *(const short8*)(VtG + (size_t)d * S_LEN + key0);
#endif
    }

    float m = -1e30f;
#pragma unroll
    for (int kt = 0; kt < NKT; ++kt) {
#pragma unroll
        for (int r = 0; r < 4; ++r) {
            int key = kbase + kt * 16 + quad * 4 + r;
            int dd = qi - key;
            int ad = dd < 0 ? -dd : dd;
            bool valid = ((unsigned)key < S_LEN) && (ad <= W);
            float s = valid ? sc[kt][r] : -1e30f;
            sc[kt][r] = s;
            m = fmaxf(m, s);
        }
    }
    m = fmaxf(m, __shfl_xor(m, 16, 64));
    m = fmaxf(m, __shfl_xor(m, 32, 64));

    float lsum = 0.f;
#pragma unroll
    for (int kt = 0; kt < NKT; ++kt) {
#pragma unroll
        for (int r = 0; r < 4; ++r) {
            float p = exp2f(sc[kt][r] - m);
            sc[kt][r] = p;
            lsum += p;
        }
    }
    lsum += __shfl_xor(lsum, 16, 64);
    lsum += __shfl_xor(lsum, 32, 64);
    const float rl = 1.f / fmaxf(lsum, 1e-30f);

    __syncthreads();   // V^T resident

    f32x4 oacc[4];
#pragma unroll
    for (int nt = 0; nt < 4; ++nt) oacc[nt] = (f32x4){0.f, 0.f, 0.f, 0.f};

#pragma unroll
    for (int kt = 0; kt < NKT; ++kt) {
        short4v pb = { f2bf(sc[kt][0]), f2bf(sc[kt][1]),
                       f2bf(sc[kt][2]), f2bf(sc[kt][3]) };
        int G = kt * 2 + (quad >> 1);
        int off = (G >> 3) * 64 + ((G & 7) ^ d7) * 8 + (quad & 1) * 4;
#pragma unroll
        for (int nt = 0; nt < 4; ++nt) {
            short4v va = *(const short4v*)(KS + (nt * 16 + lane16) * 320 + off);
            oacc[nt] = MFMA16(va, pb, oacc[nt]);
        }
    }

#pragma unroll
    for (int nt = 0; nt < 4; ++nt) {
        short4v ob = { f2bf(oacc[nt][0] * rl), f2bf(oacc[nt][1] * rl),
                       f2bf(oacc[nt][2] * rl), f2bf(oacc[nt][3] * rl) };
        *(short4v*)(attn_out + (size_t)qi * EMB + h * HD + nt * 16 + quad * 4) = ob;
    }
}

// ---------------------------------------------------------------------------
// Output projection: A = attn bf16 (DMA staged, XOR swizzle), B = Wo fp32
// (reg-staged + in-reg cvt, swizzled ds_write). 64x64 tile, BK=64, dbuf.
// ---------------------------------------------------------------------------
__global__ __launch_bounds__(256) void gemm_out64(
    const short* __restrict__ A, const float* __restrict__ Bf,
    const float* __restrict__ bias, float* __restrict__ C,
    int M, int N, int K)
{
    __shared__ __align__(16) short As[2][4352];   // 17408 B (Ct overlay needs 16896)
    __shared__ __align__(16) short Bs[2][4096];

    const int t = threadIdx.x;
    const int w = t >> 6, l = t & 63;
    const int quad = l >> 4, lane16 = l & 15;
    const int m0 = blockIdx.y * 64, n0 = blockIdx.x * 64;
    const int wm = (w >> 1) * 32, wn = (w & 1) * 32;

    f32x4 acc[2][2];
#pragma unroll
    for (int i = 0; i < 2; ++i)
#pragma unroll
        for (int j = 0; j < 2; ++j) acc[i][j] = (f32x4){0.f, 0.f, 0.f, 0.f};

    const int NKI = K >> 6;   // 12

    auto stageA = [&](int ki, int b) {
#pragma unroll
        for (int i = 0; i < 2; ++i) {
            int c = i * 256 + t;
            int r = c >> 3, kc = c & 7;
            int g = kc ^ (r & 7);
#if defined(__HIP_DEVICE_COMPILE__) && __has_builtin(__builtin_amdgcn_global_load_lds)
            __builtin_amdgcn_global_load_lds(
                (const __attribute__((address_space(1))) void*)(A + (size_t)(m0 + r) * K + ki * 64 + g * 8),
                (__attribute__((address_space(3))) void*)(As[b] + c * 8), 16, 0, 0);
#else
            *(short8*)(As[b] + c * 8) = *(const short8*)(A + (size_t)(m0 + r) * K + ki * 64 + g * 8);
#endif
        }
    };

    f32x4 rbB[2][2];
    auto loadB = [&](int ki) {
#pragma unroll
        for (int i = 0; i < 2; ++i) {
            int c = i * 256 + t;
            int r = c >> 3, gs = c & 7;
            const float* p = Bf + (size_t)(n0 + r) * K + ki * 64 + gs * 8;
            rbB[i][0] = *(const f32x4*)p;
            rbB[i][1] = *(const f32x4*)(p + 4);
        }
    };
    auto writeB = [&](int b) {
#pragma unroll
        for (int i = 0; i < 2; ++i) {
            int c = i * 256 + t;
            int r = c >> 3, gs = c & 7;
            int slot = gs ^ (r & 7);
            *(short8*)(Bs[b] + (r * 8 + slot) * 8) = cvt8(rbB[i][0], rbB[i][1]);
        }
    };

    stageA(0, 0);
    loadB(0);
    writeB(0);
    for (int kb = 0; kb < NKI; ++kb) {
        const int cur = kb & 1;
        __syncthreads();
        if (kb + 1 < NKI) { stageA(kb + 1, cur ^ 1); loadB(kb + 1); }

#pragma unroll
        for (int ks = 0; ks < 2; ++ks) {
            short8 af[2], bfr[2];
#pragma unroll
            for (int mt = 0; mt < 2; ++mt) {
                int row = wm + mt * 16 + lane16;
                int slot = (ks * 4 + quad) ^ (row & 7);
                af[mt] = *(const short8*)(As[cur] + row * 64 + slot * 8);
            }
#pragma unroll
            for (int nt = 0; nt < 2; ++nt) {
                int row = wn + nt * 16 + lane16;
                int slot = (ks * 4 + quad) ^ (row & 7);
                bfr[nt] = *(const short8*)(Bs[cur] + row * 64 + slot * 8);
            }
#pragma unroll
            for (int mt = 0; mt < 2; ++mt)
#pragma unroll
                for (int nt = 0; nt < 2; ++nt)
                    acc[mt][nt] = __builtin_amdgcn_mfma_f32_16x16x32_bf16(
                        af[mt], bfr[nt], acc[mt][nt], 0, 0, 0);
        }

        if (kb + 1 < NKI) writeB(cur ^ 1);
    }

    __syncthreads();
    float(*Ct)[66] = (float(*)[66])As;

#pragma unroll
    for (int nt = 0; nt < 2; ++nt) {
        int cl = wn + nt * 16 + lane16;
        float bv = bias[n0 + cl];
#pragma unroll
        for (int mt = 0; mt < 2; ++mt) {
#pragma unroll
            for (int r = 0; r < 4; ++r)
                Ct[wm + mt * 16 + quad * 4 + r][cl] = acc[mt][nt][r] + bv;
        }
    }
    __syncthreads();

#pragma unroll
    for (int pass = 0; pass < 4; ++pass) {
        int c = pass * 256 + t;
        int row = c >> 4, cg = c & 15;
        float4 v = { Ct[row][cg * 4], Ct[row][cg * 4 + 1],
                     Ct[row][cg * 4 + 2], Ct[row][cg * 4 + 3] };
        *(float4*)(C + (size_t)(m0 + row) * N + n0 + cg * 4) = v;
    }
}

extern "C" void kernel_launch(void* const* d_in, const int* in_sizes, int n_in,
                              void* d_out, int out_size, void* d_ws, size_t ws_size,
                              hipStream_t stream) {
    const float* x    = (const float*)d_in[0];
    const float* Wqkv = (const float*)d_in[1];
    const float* bqkv = (const float*)d_in[2];
    const float* Wo   = (const float*)d_in[3];
    const float* bo   = (const float*)d_in[4];
    const int*   wptr = (const int*)d_in[5];

    float* out = (float*)d_out;

    short* qsplit = (short*)d_ws;                          // Q|K row-major, V^T
    short* attn   = qsplit + (size_t)3 * NH * S_LEN * HD;

    dim3 blk(256);
    gemm_qkv<<<dim3(2304 / 96, S_LEN / 128), blk, 0, stream>>>(
        x, Wqkv, bqkv, qsplit, S_LEN, 2304, EMB);
    attn_win<<<dim3(S_LEN / QT * NH), blk, 0, stream>>>(qsplit, wptr, attn);
    gemm_out64<<<dim3(EMB / 64, S_LEN / 64), blk, 0, stream>>>(
        attn, Wo, bo, out, S_LEN, EMB, EMB);
}

// Round 14
// 135.002 us; speedup vs baseline: 1.0950x; 1.0352x over previous
//
#include <hip/hip_runtime.h>

// SparseWindowedAttention: B=1, S=4096, E=768, H=12, hd=64, window=128
// R14 = R11 structure (separate convert, bf16 DMA staging — known 134.2 us)
// + XCD-aware grid swizzles on both GEMMs (L2-resident weight panels).
//
//   c0: fused fp32->bf16 convert (x, Wqkv, Wo)
//   k1: qkv GEMM 128x96, dbuf DMA, XCD swizzle: XCD x owns n-cols [288x,288x+288)
//   k2: windowed attention (unchanged)
//   k3: proj 64x64 dbuf, XCD swizzle: XCD x owns m-rows [512x, 512x+512)

typedef __attribute__((ext_vector_type(8))) short short8;
typedef __attribute__((ext_vector_type(4))) short short4v;
typedef __attribute__((ext_vector_type(4))) float f32x4;

#define S_LEN 4096
#define EMB   768
#define NH    12
#define HD    64
#define QT    64
#define WMAX  128
#define NKT   20
#define QSCALE 0.18033688f   // 1/sqrt(64) * log2(e); softmax base-2

#if defined(__HIP_DEVICE_COMPILE__)
#define MFMA16(a, b, c) __builtin_amdgcn_mfma_f32_16x16x16bf16_1k(a, b, c, 0, 0, 0)
#else
#define MFMA16(a, b, c) (c)
#endif

__device__ __forceinline__ short f2bf(float f) {
    union { unsigned int i; float f; } c;
    c.f = f;
    unsigned int i = c.i;
    unsigned int r = (i + 0x7FFFu + ((i >> 16) & 1u)) >> 16;
    return (short)(unsigned short)r;
}

// fused fp32->bf16: segments [x | Wqkv | Wo]
#define NX4  (S_LEN * EMB / 4)
#define NW4  (3 * EMB * EMB / 4)
#define NO4  (EMB * EMB / 4)
__global__ __launch_bounds__(256) void convert_all(
    const float* __restrict__ x, const float* __restrict__ wqkv,
    const float* __restrict__ wo, short* __restrict__ xb,
    short* __restrict__ wqkvb, short* __restrict__ wob)
{
    int i = blockIdx.x * 256 + threadIdx.x;
    const float* src; short* dst; int off;
    if (i < NX4)            { src = x;    dst = xb;    off = i; }
    else if (i < NX4 + NW4) { src = wqkv; dst = wqkvb; off = i - NX4; }
    else                    { src = wo;   dst = wob;   off = i - NX4 - NW4; }
    float4 v = ((const float4*)src)[off];
    short4v o = { f2bf(v.x), f2bf(v.y), f2bf(v.z), f2bf(v.w) };
    *(short4v*)(dst + (size_t)off * 4) = o;
}

// ---------------------------------------------------------------------------
// QKV GEMM: C = A·B^T + bias, 128(M)x96(N), BK=32, dbuf DMA, 1-D grid 768.
// XCD swizzle (id%8 round-robin assumption): xcd = id&7 owns the 3 n-tiles
// [xcd*288, xcd*288+288) -> its 442 KB Wqkv slice stays L2-resident.
// Epilogue: V -> direct V^T 8B stores; Q/K -> LDS round-trip, short8 stores.
// ---------------------------------------------------------------------------
__global__ __launch_bounds__(256) void gemm_qkv(
    const short* __restrict__ A, const short* __restrict__ B,
    const float* __restrict__ bias, short* __restrict__ Cv,
    int M, int N, int K)
{
    __shared__ __align__(16) short smem[2 * 4096 + 2 * 3072];
    short* As0 = smem;
    short* Bs0 = smem + 2 * 4096;

    const int t = threadIdx.x;
    const int w = t >> 6, l = t & 63;
    const int quad = l >> 4, lane16 = l & 15;

    const int id = blockIdx.x;          // 0..767
    const int xcd = id & 7, j = id >> 3;   // j 0..95
    const int m0 = (j / 3) * 128;          // 32 m-tiles
    const int n0 = (xcd * 3 + (j % 3)) * 96;   // XCD-local n range
    const int wm = (w >> 1) * 64, wn = (w & 1) * 48;

    f32x4 acc[4][3];
#pragma unroll
    for (int i = 0; i < 4; ++i)
#pragma unroll
        for (int jj = 0; jj < 3; ++jj) acc[i][jj] = (f32x4){0.f, 0.f, 0.f, 0.f};

    const int NKI = K >> 5;   // 24

    auto stage = [&](int ki, int b) {
        short* Asb = As0 + b * 4096;
        short* Bsb = Bs0 + b * 3072;
#pragma unroll
        for (int i = 0; i < 4; ++i) {
            int c = i * 256 + t;
            if (c < 512) {
                int r = c >> 2, kc = c & 3;
#if defined(__HIP_DEVICE_COMPILE__) && __has_builtin(__builtin_amdgcn_global_load_lds)
                __builtin_amdgcn_global_load_lds(
                    (const __attribute__((address_space(1))) void*)(A + (size_t)(m0 + r) * K + ki * 32 + kc * 8),
                    (__attribute__((address_space(3))) void*)(Asb + c * 8), 16, 0, 0);
#else
                *(short8*)(Asb + c * 8) = *(const short8*)(A + (size_t)(m0 + r) * K + ki * 32 + kc * 8);
#endif
            } else if (c < 896) {
                int cb = c - 512;
                int r = cb >> 2, kc = cb & 3;
#if defined(__HIP_DEVICE_COMPILE__) && __has_builtin(__builtin_amdgcn_global_load_lds)
                __builtin_amdgcn_global_load_lds(
                    (const __attribute__((address_space(1))) void*)(B + (size_t)(n0 + r) * K + ki * 32 + kc * 8),
                    (__attribute__((address_space(3))) void*)(Bsb + cb * 8), 16, 0, 0);
#else
                *(short8*)(Bsb + cb * 8) = *(const short8*)(B + (size_t)(n0 + r) * K + ki * 32 + kc * 8);
#endif
            }
        }
    };

    stage(0, 0);
    for (int kb = 0; kb < NKI; ++kb) {
        const int cur = kb & 1;
        __syncthreads();
        if (kb + 1 < NKI) stage(kb + 1, cur ^ 1);

        const short* Asb = As0 + cur * 4096;
        const short* Bsb = Bs0 + cur * 3072;
        short8 af[4], bfr[3];
#pragma unroll
        for (int mt = 0; mt < 4; ++mt)
            af[mt] = *(const short8*)(Asb + (wm + mt * 16 + lane16) * 32 + quad * 8);
#pragma unroll
        for (int nt = 0; nt < 3; ++nt)
            bfr[nt] = *(const short8*)(Bsb + (wn + nt * 16 + lane16) * 32 + quad * 8);
#pragma unroll
        for (int mt = 0; mt < 4; ++mt)
#pragma unroll
            for (int nt = 0; nt < 3; ++nt)
                acc[mt][nt] = __builtin_amdgcn_mfma_f32_16x16x32_bf16(
                    af[mt], bfr[nt], acc[mt][nt], 0, 0, 0);
    }

    __syncthreads();
    short(*Ct)[100] = (short(*)[100])smem;

#pragma unroll
    for (int nt = 0; nt < 3; ++nt) {
        int col = n0 + wn + nt * 16 + lane16;
        float bv = bias[col];
        int h = col / 192;
        int rem = col - h * 192;
        int ty = rem >> 6, d = rem & 63;
        if (ty == 2) {
            short* vt = Cv + ((size_t)2 * NH * S_LEN) * HD + ((size_t)h * HD + d) * S_LEN;
#pragma unroll
            for (int mt = 0; mt < 4; ++mt) {
                int row0 = m0 + wm + mt * 16 + quad * 4;
                short4v o = { f2bf(acc[mt][nt][0] + bv), f2bf(acc[mt][nt][1] + bv),
                              f2bf(acc[mt][nt][2] + bv), f2bf(acc[mt][nt][3] + bv) };
                *(short4v*)(vt + row0) = o;
            }
        } else {
            float s = (ty == 0) ? QSCALE : 1.f;
            int cl = wn + nt * 16 + lane16;
#pragma unroll
            for (int mt = 0; mt < 4; ++mt) {
#pragma unroll
                for (int r = 0; r < 4; ++r)
                    Ct[wm + mt * 16 + quad * 4 + r][cl] = f2bf((acc[mt][nt][r] + bv) * s);
            }
        }
    }
    __syncthreads();

#pragma unroll
    for (int pass = 0; pass < 6; ++pass) {
        int c = pass * 256 + t;
        int row = c / 12, cg = c - row * 12;
        int col0 = n0 + cg * 8;
        int h = col0 / 192;
        int rem = col0 - h * 192;
        int ty = rem >> 6;
        if (ty == 2) continue;
        int d0 = rem - ty * 64;
        short* dst = Cv + (((size_t)ty * NH + h) * S_LEN + (m0 + row)) * HD + d0;
        *(short8*)dst = *(const short8*)(&Ct[row][cg * 8]);
    }
}

// ---------------------------------------------------------------------------
// Windowed attention (unchanged from R11).
// ---------------------------------------------------------------------------
__global__ __launch_bounds__(256, 3) void attn_win(
    const short* __restrict__ qsplit, const int* __restrict__ wptr,
    short* __restrict__ attn_out)
{
    __shared__ __align__(16) short KS[320 * 64];   // 40960 B

    const int t = threadIdx.x;
    const int w = t >> 6, l = t & 63;
    const int quad = l >> 4, lane16 = l & 15;

    const int id = blockIdx.x;
    const int xcd = id & 7, j = id >> 3;
    const int h = j >> 3;
    const int q0 = ((xcd << 3) + (j & 7)) * QT;
    const int W = *wptr;
    const int kbase = q0 - WMAX;

    const short* Qh  = qsplit + (size_t)h * S_LEN * HD;
    const short* Kh  = qsplit + (size_t)(NH + h) * S_LEN * HD;
    const short* VtG = qsplit + (size_t)2 * NH * S_LEN * HD + (size_t)h * HD * S_LEN;

#pragma unroll
    for (int i = 0; i < 10; ++i) {
        int c = i * 256 + t;
        int r = c >> 3, gs = c & 7;
        int g = gs ^ (r & 7);
        int idx = min(max(kbase + r, 0), S_LEN - 1);
#if defined(__HIP_DEVICE_COMPILE__) && __has_builtin(__builtin_amdgcn_global_load_lds)
        __builtin_amdgcn_global_load_lds(
            (const __attribute__((address_space(1))) void*)(Kh + (size_t)idx * HD + g * 8),
            (__attribute__((address_space(3))) void*)(KS + c * 8), 16, 0, 0);
#else
        *(short8*)(KS + c * 8) = *(const short8*)(Kh + (size_t)idx * HD + g * 8);
#endif
    }
    const int qi = q0 + w * 16 + lane16;
    const short* qp = Qh + (size_t)qi * HD;
    short8 bq0 = *(const short8*)(qp + quad * 8);
    short8 bq1 = *(const short8*)(qp + 32 + quad * 8);

    __syncthreads();   // K resident

    f32x4 sc[NKT];
    const int d7 = lane16 & 7;
    const int s0 = (quad ^ d7) * 8;
    const int s1 = ((quad + 4) ^ d7) * 8;
#pragma unroll
    for (int kt = 0; kt < NKT; ++kt) {
        const short* kp = KS + (kt * 16 + lane16) * 64;
        short8 a0 = *(const short8*)(kp + s0);
        short8 a1 = *(const short8*)(kp + s1);
        f32x4 a = (f32x4){0.f, 0.f, 0.f, 0.f};
        a = __builtin_amdgcn_mfma_f32_16x16x32_bf16(a0, bq0, a, 0, 0, 0);
        a = __builtin_amdgcn_mfma_f32_16x16x32_bf16(a1, bq1, a, 0, 0, 0);
        sc[kt] = a;
    }

    __syncthreads();   // WAR: K reads done; KS free for V^T

#pragma unroll
    for (int i = 0; i < 10; ++i) {
        int c = i * 256 + t;
        int d = c / 40;
        int slot = c - d * 40;
        int sg = slot >> 3, s = slot & 7;
        int g = s ^ (d & 7);
        int key0 = kbase + sg * 64 + g * 8;
        key0 = min(max(key0, 0), S_LEN - 8);
#if defined(__HIP_DEVICE_COMPILE__) && __has_builtin(__builtin_amdgcn_global_load_lds)
        __builtin_amdgcn_global_load_lds(
            (const __attribute__((address_space(1))) void*)(VtG + (size_t)d * S_LEN + key0),
            (__attribute__((address_space(3))) void*)(KS + c * 8), 16, 0, 0);
#else
        *(short8*)(KS + c * 8) = *(const short8*)(VtG + (size_t)d * S_LEN + key0);
#endif
    }

    float m = -1e30f;
#pragma unroll
    for (int kt = 0; kt < NKT; ++kt) {
#pragma unroll
        for (int r = 0; r < 4; ++r) {
            int key = kbase + kt * 16 + quad * 4 + r;
            int dd = qi - key;
            int ad = dd < 0 ? -dd : dd;
            bool valid = ((unsigned)key < S_LEN) && (ad <= W);
            float s = valid ? sc[kt][r] : -1e30f;
            sc[kt][r] = s;
            m = fmaxf(m, s);
        }
    }
    m = fmaxf(m, __shfl_xor(m, 16, 64));
    m = fmaxf(m, __shfl_xor(m, 32, 64));

    float lsum = 0.f;
#pragma unroll
    for (int kt = 0; kt < NKT; ++kt) {
#pragma unroll
        for (int r = 0; r < 4; ++r) {
            float p = exp2f(sc[kt][r] - m);
            sc[kt][r] = p;
            lsum += p;
        }
    }
    lsum += __shfl_xor(lsum, 16, 64);
    lsum += __shfl_xor(lsum, 32, 64);
    const float rl = 1.f / fmaxf(lsum, 1e-30f);

    __syncthreads();   // V^T resident

    f32x4 oacc[4];
#pragma unroll
    for (int nt = 0; nt < 4; ++nt) oacc[nt] = (f32x4){0.f, 0.f, 0.f, 0.f};

#pragma unroll
    for (int kt = 0; kt < NKT; ++kt) {
        short4v pb = { f2bf(sc[kt][0]), f2bf(sc[kt][1]),
                       f2bf(sc[kt][2]), f2bf(sc[kt][3]) };
        int G = kt * 2 + (quad >> 1);
        int off = (G >> 3) * 64 + ((G & 7) ^ d7) * 8 + (quad & 1) * 4;
#pragma unroll
        for (int nt = 0; nt < 4; ++nt) {
            short4v va = *(const short4v*)(KS + (nt * 16 + lane16) * 320 + off);
            oacc[nt] = MFMA16(va, pb, oacc[nt]);
        }
    }

#pragma unroll
    for (int nt = 0; nt < 4; ++nt) {
        short4v ob = { f2bf(oacc[nt][0] * rl), f2bf(oacc[nt][1] * rl),
                       f2bf(oacc[nt][2] * rl), f2bf(oacc[nt][3] * rl) };
        *(short4v*)(attn_out + (size_t)qi * EMB + h * HD + nt * 16 + quad * 4) = ob;
    }
}

// ---------------------------------------------------------------------------
// Output projection: 64x64 tile, BK=64, dbuf DMA, 1-D grid 768, XCD swizzle:
// xcd = id&7 owns m-rows [xcd*512, xcd*512+512) -> attn slice L2-resident.
// ---------------------------------------------------------------------------
__global__ __launch_bounds__(256) void gemm_out64(
    const short* __restrict__ A, const short* __restrict__ B,
    const float* __restrict__ bias, float* __restrict__ C,
    int M, int N, int K)
{
    __shared__ __align__(16) short As[2][4352];
    __shared__ __align__(16) short Bs[2][4096];

    const int t = threadIdx.x;
    const int w = t >> 6, l = t & 63;
    const int quad = l >> 4, lane16 = l & 15;

    const int id = blockIdx.x;          // 0..767
    const int xcd = id & 7, j = id >> 3;   // j 0..95
    const int m0 = (xcd * 8 + (j & 7)) * 64;   // XCD-local m range
    const int n0 = (j >> 3) * 64;              // 12 n-tiles
    const int wm = (w >> 1) * 32, wn = (w & 1) * 32;

    f32x4 acc[2][2];
#pragma unroll
    for (int i = 0; i < 2; ++i)
#pragma unroll
        for (int jj = 0; jj < 2; ++jj) acc[i][jj] = (f32x4){0.f, 0.f, 0.f, 0.f};

    const int NKI = K >> 6;   // 12

    auto stage = [&](int ki, int b) {
#pragma unroll
        for (int i = 0; i < 2; ++i) {
            int c = i * 256 + t;
            int r = c >> 3, kc = c & 7;
            int g = kc ^ (r & 7);
#if defined(__HIP_DEVICE_COMPILE__) && __has_builtin(__builtin_amdgcn_global_load_lds)
            __builtin_amdgcn_global_load_lds(
                (const __attribute__((address_space(1))) void*)(A + (size_t)(m0 + r) * K + ki * 64 + g * 8),
                (__attribute__((address_space(3))) void*)(As[b] + c * 8), 16, 0, 0);
            __builtin_amdgcn_global_load_lds(
                (const __attribute__((address_space(1))) void*)(B + (size_t)(n0 + r) * K + ki * 64 + g * 8),
                (__attribute__((address_space(3))) void*)(Bs[b] + c * 8), 16, 0, 0);
#else
            *(short8*)(As[b] + c * 8) = *(const short8*)(A + (size_t)(m0 + r) * K + ki * 64 + g * 8);
            *(short8*)(Bs[b] + c * 8) = *(const short8*)(B + (size_t)(n0 + r) * K + ki * 64 + g * 8);
#endif
        }
    };

    stage(0, 0);
    for (int kb = 0; kb < NKI; ++kb) {
        const int cur = kb & 1;
        __syncthreads();
        if (kb + 1 < NKI) stage(kb + 1, cur ^ 1);

#pragma unroll
        for (int ks = 0; ks < 2; ++ks) {
            short8 af[2], bfr[2];
#pragma unroll
            for (int mt = 0; mt < 2; ++mt) {
                int row = wm + mt * 16 + lane16;
                int slot = (ks * 4 + quad) ^ (row & 7);
                af[mt] = *(const short8*)(As[cur] + row * 64 + slot * 8);
            }
#pragma unroll
            for (int nt = 0; nt < 2; ++nt) {
                int row = wn + nt * 16 + lane16;
                int slot = (ks * 4 + quad) ^ (row & 7);
                bfr[nt] = *(const short8*)(Bs[cur] + row * 64 + slot * 8);
            }
#pragma unroll
            for (int mt = 0; mt < 2; ++mt)
#pragma unroll
                for (int nt = 0; nt < 2; ++nt)
                    acc[mt][nt] = __builtin_amdgcn_mfma_f32_16x16x32_bf16(
                        af[mt], bfr[nt], acc[mt][nt], 0, 0, 0);
        }
    }

    __syncthreads();
    float(*Ct)[66] = (float(*)[66])As;

#pragma unroll
    for (int nt = 0; nt < 2; ++nt) {
        int cl = wn + nt * 16 + lane16;
        float bv = bias[n0 + cl];
#pragma unroll
        for (int mt = 0; mt < 2; ++mt) {
#pragma unroll
            for (int r = 0; r < 4; ++r)
                Ct[wm + mt * 16 + quad * 4 + r][cl] = acc[mt][nt][r] + bv;
        }
    }
    __syncthreads();

#pragma unroll
    for (int pass = 0; pass < 4; ++pass) {
        int c = pass * 256 + t;
        int row = c >> 4, cg = c & 15;
        float4 v = { Ct[row][cg * 4], Ct[row][cg * 4 + 1],
                     Ct[row][cg * 4 + 2], Ct[row][cg * 4 + 3] };
        *(float4*)(C + (size_t)(m0 + row) * N + n0 + cg * 4) = v;
    }
}

extern "C" void kernel_launch(void* const* d_in, const int* in_sizes, int n_in,
                              void* d_out, int out_size, void* d_ws, size_t ws_size,
                              hipStream_t stream) {
    const float* x    = (const float*)d_in[0];
    const float* Wqkv = (const float*)d_in[1];
    const float* bqkv = (const float*)d_in[2];
    const float* Wo   = (const float*)d_in[3];
    const float* bo   = (const float*)d_in[4];
    const int*   wptr = (const int*)d_in[5];

    float* out = (float*)d_out;

    short* xb     = (short*)d_ws;
    short* wqkvb  = xb     + (size_t)S_LEN * EMB;
    short* wob    = wqkvb  + (size_t)3 * EMB * EMB;
    short* qsplit = wob    + (size_t)EMB * EMB;
    short* attn   = qsplit + (size_t)3 * NH * S_LEN * HD;

    dim3 blk(256);
    convert_all<<<dim3((NX4 + NW4 + NO4) / 256), blk, 0, stream>>>(
        x, Wqkv, Wo, xb, wqkvb, wob);
    gemm_qkv<<<dim3(768), blk, 0, stream>>>(
        xb, wqkvb, bqkv, qsplit, S_LEN, 2304, EMB);
    attn_win<<<dim3(S_LEN / QT * NH), blk, 0, stream>>>(qsplit, wptr, attn);
    gemm_out64<<<dim3(768), blk, 0, stream>>>(
        attn, wob, bo, out, S_LEN, EMB, EMB);
}